// Round 6
// baseline (165.173 us; speedup 1.0000x reference)
//
#include <hip/hip_runtime.h>

typedef __attribute__((ext_vector_type(8))) short short8;
typedef __attribute__((ext_vector_type(4))) float floatx4;

#define N_   64
#define CIN  64
#define T_   128
#define V_   25
#define CO   128
#define MCNT 204800.0f

// ws byte offsets
#define OFF_WCF  0            // ushort[49152]  Wc A-frags [mt8][ks6][lane64][8]
#define OFF_WDF  98304        // ushort[16384]  Wd A-frags [mt8][ks2][lane64][8]
#define OFF_AF   131072       // ushort[3072]   adjacency B-frags [k3][nt2][lane64][8]
#define OFF_BC2  137216       // float[128][32] aggregated bias
#define OFF_P1   153600       // float[4][128][2048] per-block stat partials
#define OFF_SUM  4347904      // float[512]
#define OFF_STAT 4349952      // float[3][128]  s1, s2, h1+h2

__device__ __forceinline__ ushort f2bf(float f) {
    uint u = __float_as_uint(f);
    return (ushort)((u + 0x7FFFu + ((u >> 16) & 1u)) >> 16);  // RNE
}
__device__ __forceinline__ uint pack2(float a, float b) {
    return (uint)f2bf(a) | ((uint)f2bf(b) << 16);
}

// ---------------- k0: weight/adjacency fragment prep ----------------
__global__ void k0_prep(const float* __restrict__ A, const float* __restrict__ Wc,
                        const float* __restrict__ bc, const float* __restrict__ Wd,
                        void* __restrict__ wsv) {
    char* wsb = (char*)wsv;
    ushort* WCF = (ushort*)(wsb + OFF_WCF);
    ushort* WDF = (ushort*)(wsb + OFF_WDF);
    ushort* AFp = (ushort*)(wsb + OFF_AF);
    float*  BC2 = (float*)(wsb + OFF_BC2);
    int tid = threadIdx.x;
    for (int e = tid; e < 49152; e += 256) {
        int fe = e >> 3, el = e & 7;
        int l = fe & 63, q = fe >> 6;
        int mt = q / 6, ks = q % 6;
        int j = ks*32 + (l>>4)*8 + el;      // j = (k,ci) contraction index
        int c = mt*16 + (l & 15);
        int k = j >> 6, ci = j & 63;
        WCF[e] = f2bf(Wc[(k*CO + c)*CIN + ci]);
    }
    for (int e = tid; e < 16384; e += 256) {
        int fe = e >> 3, el = e & 7;
        int l = fe & 63, q = fe >> 6;
        int mt = q >> 1, ks = q & 1;
        int ci = ks*32 + (l>>4)*8 + el;
        int c = mt*16 + (l & 15);
        WDF[e] = f2bf(Wd[c*CIN + ci]);
    }
    for (int e = tid; e < 3072; e += 256) {
        int fe = e >> 3, el = e & 7;
        int l = fe & 63, q = fe >> 6;
        int k = q >> 1, nt = q & 1;
        int w = nt*16 + (l & 15);
        int v = (l>>4)*8 + el;
        AFp[e] = (v < V_ && w < V_) ? f2bf(A[(k*V_ + v)*V_ + w]) : (ushort)0;
    }
    for (int e = tid; e < 4096; e += 256) {
        int c = e >> 5, w = e & 31;
        float s = 0.f;
        if (w < V_) {
            for (int k = 0; k < 3; ++k) {
                float cs = 0.f;
                for (int v = 0; v < V_; ++v) cs += A[(k*V_ + v)*V_ + w];
                s += bc[k*CO + c] * cs;
            }
        }
        BC2[e] = s;
    }
}

// ---------------- k1: MFMA forward; stores packed (y2,res) bf16 pair; stats ----------------
// grid 1024 = n(64) x tchunk(16, 8 t each); block 1024 = 16 waves (ch = wv&7, th = wv>>3)
__global__ __launch_bounds__(1024, 2) void k1_main(
        const float* __restrict__ x, const float* __restrict__ bd,
        void* __restrict__ wsv, uint* __restrict__ outu) {
    char* wsb = (char*)wsv;
    const ushort* WCF = (const ushort*)(wsb + OFF_WCF);
    const ushort* WDF = (const ushort*)(wsb + OFF_WDF);
    const ushort* AF  = (const ushort*)(wsb + OFF_AF);
    const float*  BC2 = (const float*)(wsb + OFF_BC2);
    float* P1 = (float*)(wsb + OFF_P1);

    __shared__ ushort XR[16384];   // [ci64][t8][v32] bf16, 16B-slot XOR swizzle (2-bit key)
    __shared__ ushort BB[16384];   // B-frag buffer: [ks2][ntm16][lane64][8]
    short8* XR8 = (short8*)XR;
    short8* BB8 = (short8*)BB;
    uint*   XRu = (uint*)XR;
    uint*   BBu = (uint*)BB;

    const int tid = threadIdx.x;
    const int l = tid & 63, wv = tid >> 6;
    const int ch = wv & 7, th = wv >> 3;
    const int blk = blockIdx.x;
    const int nb = blk & 63, tcb = blk >> 6;
    const long xbase = (long)nb * (CIN * T_ * V_);
    const int tg0 = tcb * 8;

    // ---- stage x -> XR ----
    #pragma unroll
    for (int i = 0; i < 8; ++i) {
        int p = tid + i * 1024;
        int ci = p >> 7, rem = p & 127, t = rem >> 4, vp = rem & 15, v = vp * 2;
        float f0 = 0.f, f1 = 0.f;
        if (v < V_)     f0 = x[xbase + ci*(T_*V_) + (tg0 + t)*V_ + v];
        if (v + 1 < V_) f1 = x[xbase + ci*(T_*V_) + (tg0 + t)*V_ + v + 1];
        int idx = (ci*8 + t)*16 + 4*((vp >> 2) ^ (ci & 3)) + (vp & 3);
        XRu[idx] = (uint)f2bf(f0) | ((uint)f2bf(f1) << 16);
    }

    short8 wcf[6];
    #pragma unroll
    for (int ks = 0; ks < 6; ++ks)
        wcf[ks] = *(const short8*)(WCF + ((ch*6 + ks)*64 + l)*8);

    __syncthreads();

    // ---- main path: agg (MFMA) -> y2 GEMM (MFMA) ----
    const int t_a = wv & 7, nt_a = wv >> 3;      // agg role: one (t, nt) pair per wave
    short8 xf[4];
    #pragma unroll
    for (int mt = 0; mt < 4; ++mt) {
        int ci = mt*16 + (l & 15), vg = l >> 4;
        xf[mt] = XR8[(ci*8 + t_a)*4 + (vg ^ (ci & 3))];
    }
    floatx4 acc[8];
    #pragma unroll
    for (int i = 0; i < 8; ++i) acc[i] = (floatx4){0,0,0,0};

    for (int k = 0; k < 3; ++k) {
        __syncthreads();
        short8 am = *(const short8*)(AF + ((k*2 + nt_a)*64 + l)*8);
        int ntm_a = t_a*2 + nt_a;
        #pragma unroll
        for (int mt = 0; mt < 4; ++mt) {
            floatx4 agc = __builtin_amdgcn_mfma_f32_16x16x32_bf16(
                xf[mt], am, (floatx4){0,0,0,0}, 0, 0, 0);
            int kb = mt >> 1;
            #pragma unroll
            for (int rp = 0; rp < 4; rp += 2) {
                int jo = (l >> 4)*4 + rp;
                int lf = (l & 15) + 16*((mt & 1)*2 + (jo >> 3));
                int ef = jo & 7;
                BBu[(((kb*16 + ntm_a)*64 + lf)*16 + ef*2) >> 2] = pack2(agc[rp], agc[rp+1]);
            }
        }
        __syncthreads();
        #pragma unroll
        for (int kb = 0; kb < 2; ++kb)
            #pragma unroll
            for (int m = 0; m < 8; ++m)
                acc[m] = __builtin_amdgcn_mfma_f32_16x16x32_bf16(
                    wcf[k*2 + kb], BB8[(kb*16 + th*8 + m)*64 + l], acc[m], 0, 0, 0);
    }

    // ---- y2: add bias, keep values in acc, accumulate stats ----
    const int cbase = ch*16 + (l >> 4)*4;
    float ys[4] = {0,0,0,0}, yss[4] = {0,0,0,0};
    #pragma unroll
    for (int m = 0; m < 8; ++m) {
        int n = (th*8 + m)*16 + (l & 15), w = n & 31;
        bool valid = w < V_;
        #pragma unroll
        for (int r = 0; r < 4; ++r) {
            float val = acc[m][r] + BC2[(cbase + r)*32 + w];
            acc[m][r] = val;
            if (valid) { ys[r] += val; yss[r] += val*val; }
        }
    }
    #pragma unroll
    for (int m = 1; m < 16; m <<= 1)
        #pragma unroll
        for (int r = 0; r < 4; ++r) {
            ys[r]  += __shfl_xor(ys[r],  m);
            yss[r] += __shfl_xor(yss[r], m);
        }
    if ((l & 15) == 0)
        #pragma unroll
        for (int r = 0; r < 4; ++r) {
            int c = cbase + r;
            P1[(0*128 + c)*2048 + blk*2 + th] = ys[r];
            P1[(1*128 + c)*2048 + blk*2 + th] = yss[r];
        }

    // ---- residual: rebuild BB with x B-frags (K=ci), MFMA, pack+store, stats ----
    __syncthreads();   // all waves done reading BB from main GEMM
    #pragma unroll
    for (int i = 0; i < 2; ++i) {
        int task = tid + i*1024;
        int fid = task >> 6, tl = task & 63;
        int n = (fid & 15)*16 + (tl & 15), t = n >> 5, v = n & 31;
        short8 r8;
        #pragma unroll
        for (int e = 0; e < 8; ++e) {
            int ci = (fid >> 4)*32 + (tl >> 4)*8 + e;
            r8[e] = (short)XR[(ci*8 + t)*32 + 8*((v >> 3) ^ (ci & 3)) + (v & 7)];
        }
        BB8[fid*64 + tl] = r8;
    }
    __syncthreads();

    short8 wdf[2];
    #pragma unroll
    for (int ks = 0; ks < 2; ++ks)
        wdf[ks] = *(const short8*)(WDF + ((ch*2 + ks)*64 + l)*8);
    float bdv[4];
    #pragma unroll
    for (int r = 0; r < 4; ++r) bdv[r] = bd[cbase + r];

    const long obase = (long)nb * 409600 + (long)tg0 * 25;
    float rs[4] = {0,0,0,0}, rss[4] = {0,0,0,0};
    #pragma unroll
    for (int g = 0; g < 2; ++g) {
        floatx4 racc[4];
        #pragma unroll
        for (int m = 0; m < 4; ++m) racc[m] = (floatx4){0,0,0,0};
        #pragma unroll
        for (int ks = 0; ks < 2; ++ks)
            #pragma unroll
            for (int m = 0; m < 4; ++m)
                racc[m] = __builtin_amdgcn_mfma_f32_16x16x32_bf16(
                    wdf[ks], BB8[(ks*16 + th*8 + g*4 + m)*64 + l], racc[m], 0, 0, 0);
        #pragma unroll
        for (int m = 0; m < 4; ++m) {
            int ntm = th*8 + g*4 + m;
            int n = ntm*16 + (l & 15), t = n >> 5, w = n & 31;
            bool valid = w < V_;
            #pragma unroll
            for (int r = 0; r < 4; ++r) {
                float rv = racc[m][r] + bdv[r];
                if (valid) {
                    rs[r] += rv; rss[r] += rv*rv;
                    outu[obase + (long)(cbase + r)*3200 + t*25 + w] = pack2(acc[g*4 + m][r], rv);
                }
            }
        }
    }
    #pragma unroll
    for (int m = 1; m < 16; m <<= 1)
        #pragma unroll
        for (int r = 0; r < 4; ++r) {
            rs[r]  += __shfl_xor(rs[r],  m);
            rss[r] += __shfl_xor(rss[r], m);
        }
    if ((l & 15) == 0)
        #pragma unroll
        for (int r = 0; r < 4; ++r) {
            int c = cbase + r;
            P1[(2*128 + c)*2048 + blk*2 + th] = rs[r];
            P1[(3*128 + c)*2048 + blk*2 + th] = rss[r];
        }
}

// ---------------- k2a/k2b: deterministic stat reduction + folding ----------------
__global__ void k2a(void* __restrict__ wsv) {
    char* wsb = (char*)wsv;
    const float* P1 = (const float*)(wsb + OFF_P1);
    float* SUM = (float*)(wsb + OFF_SUM);
    __shared__ float red[256];
    int gc = blockIdx.x;
    float s = 0.f;
    for (int i = threadIdx.x; i < 2048; i += 256) s += P1[(long)gc*2048 + i];
    red[threadIdx.x] = s; __syncthreads();
    for (int st = 128; st > 0; st >>= 1) {
        if (threadIdx.x < st) red[threadIdx.x] += red[threadIdx.x + st];
        __syncthreads();
    }
    if (threadIdx.x == 0) SUM[gc] = red[0];
}

__global__ void k2b(const float* __restrict__ gamma, const float* __restrict__ beta,
                    const float* __restrict__ gamma_d, const float* __restrict__ beta_d,
                    void* __restrict__ wsv) {
    char* wsb = (char*)wsv;
    const float* SUM = (const float*)(wsb + OFF_SUM);
    float* STAT = (float*)(wsb + OFF_STAT);
    int c = threadIdx.x;
    if (c < 128) {
        float my = SUM[c] / MCNT;
        float vy = fmaxf(SUM[128 + c] / MCNT - my*my, 0.f);
        float s1 = rsqrtf(vy + 1e-5f) * gamma[c];
        float h1 = beta[c] - my * s1;
        float mr = SUM[256 + c] / MCNT;     // res stats already include bd
        float vr = fmaxf(SUM[384 + c] / MCNT - mr*mr, 0.f);
        float s2 = rsqrtf(vr + 1e-5f) * gamma_d[c];
        float h2 = beta_d[c] - mr * s2;
        STAT[c] = s1; STAT[128 + c] = s2; STAT[256 + c] = h1 + h2;
    }
}

// ---------------- k3: in-place streaming map: packed(y2,res) -> relu(y2*s1+res*s2+h) ----------------
__global__ __launch_bounds__(256) void k3_map(void* __restrict__ wsv, uint* __restrict__ outu) {
    const float* STAT = (const float*)((const char*)wsv + OFF_STAT);
    __shared__ float sS[384];
    for (int i = threadIdx.x; i < 384; i += 256) sS[i] = STAT[i];
    __syncthreads();
    const int total4 = 6553600;                 // 26214400 uints / 4
    int stride = gridDim.x * blockDim.x;
    for (int j = blockIdx.x * blockDim.x + threadIdx.x; j < total4; j += stride) {
        uint4 u = ((const uint4*)outu)[j];
        int c = (j / 800) & 127;                // c = (4j / 3200) % 128
        float s1 = sS[c], s2 = sS[128 + c], h = sS[256 + c];
        float4 o;
        o.x = fmaxf(__uint_as_float(u.x << 16) * s1 + __uint_as_float(u.x & 0xFFFF0000u) * s2 + h, 0.f);
        o.y = fmaxf(__uint_as_float(u.y << 16) * s1 + __uint_as_float(u.y & 0xFFFF0000u) * s2 + h, 0.f);
        o.z = fmaxf(__uint_as_float(u.z << 16) * s1 + __uint_as_float(u.z & 0xFFFF0000u) * s2 + h, 0.f);
        o.w = fmaxf(__uint_as_float(u.w << 16) * s1 + __uint_as_float(u.w & 0xFFFF0000u) * s2 + h, 0.f);
        ((float4*)outu)[j] = o;
    }
}

extern "C" void kernel_launch(void* const* d_in, const int* in_sizes, int n_in,
                              void* d_out, int out_size, void* d_ws, size_t ws_size,
                              hipStream_t stream) {
    const float* x       = (const float*)d_in[0];
    const float* A       = (const float*)d_in[1];
    const float* Wc      = (const float*)d_in[2];
    const float* bc      = (const float*)d_in[3];
    const float* gamma   = (const float*)d_in[4];
    const float* beta    = (const float*)d_in[5];
    const float* Wd      = (const float*)d_in[6];
    const float* bd      = (const float*)d_in[7];
    const float* gamma_d = (const float*)d_in[8];
    const float* beta_d  = (const float*)d_in[9];
    uint* outu = (uint*)d_out;

    k0_prep<<<1, 256, 0, stream>>>(A, Wc, bc, Wd, d_ws);
    k1_main<<<1024, 1024, 0, stream>>>(x, bd, d_ws, outu);
    k2a<<<512, 256, 0, stream>>>(d_ws);
    k2b<<<1, 128, 0, stream>>>(gamma, beta, gamma_d, beta_d, d_ws);
    k3_map<<<2048, 256, 0, stream>>>(d_ws, outu);
}

// Round 8
// 159.276 us; speedup vs baseline: 1.0370x; 1.0370x over previous
//
#include <hip/hip_runtime.h>

typedef __attribute__((ext_vector_type(8))) short short8;
typedef __attribute__((ext_vector_type(4))) float floatx4;

#define N_   64
#define CIN  64
#define T_   128
#define V_   25
#define CO   128
#define MCNT 204800.0f

// ws byte offsets
#define OFF_WCF  0            // ushort[49152]  Wc A-frags [mt8][ks6][lane64][8]
#define OFF_WDF  98304        // ushort[16384]  Wd A-frags [mt8][ks2][lane64][8]
#define OFF_AF   131072       // ushort[3072]   adjacency B-frags [k3][nt2][lane64][8]
#define OFF_BC2  137216       // float[128][32] aggregated bias
#define OFF_P1   153600       // float[4][128][2048] per-block stat partials
#define OFF_SUM  4347904      // float[512]
#define OFF_STAT 4349952      // float[3][128]  s1, s2, h1+h2

__device__ __forceinline__ ushort f2bf(float f) {
    uint u = __float_as_uint(f);
    return (ushort)((u + 0x7FFFu + ((u >> 16) & 1u)) >> 16);  // RNE
}
__device__ __forceinline__ uint pack2(float a, float b) {
    return (uint)f2bf(a) | ((uint)f2bf(b) << 16);
}

// ---------------- k0: weight/adjacency fragment prep ----------------
__global__ void k0_prep(const float* __restrict__ A, const float* __restrict__ Wc,
                        const float* __restrict__ bc, const float* __restrict__ Wd,
                        void* __restrict__ wsv) {
    char* wsb = (char*)wsv;
    ushort* WCF = (ushort*)(wsb + OFF_WCF);
    ushort* WDF = (ushort*)(wsb + OFF_WDF);
    ushort* AFp = (ushort*)(wsb + OFF_AF);
    float*  BC2 = (float*)(wsb + OFF_BC2);
    int tid = threadIdx.x;
    for (int e = tid; e < 49152; e += 256) {
        int fe = e >> 3, el = e & 7;
        int l = fe & 63, q = fe >> 6;
        int mt = q / 6, ks = q % 6;
        int j = ks*32 + (l>>4)*8 + el;      // j = (k,ci) contraction index
        int c = mt*16 + (l & 15);
        int k = j >> 6, ci = j & 63;
        WCF[e] = f2bf(Wc[(k*CO + c)*CIN + ci]);
    }
    for (int e = tid; e < 16384; e += 256) {
        int fe = e >> 3, el = e & 7;
        int l = fe & 63, q = fe >> 6;
        int mt = q >> 1, ks = q & 1;
        int ci = ks*32 + (l>>4)*8 + el;
        int c = mt*16 + (l & 15);
        WDF[e] = f2bf(Wd[c*CIN + ci]);
    }
    for (int e = tid; e < 3072; e += 256) {
        int fe = e >> 3, el = e & 7;
        int l = fe & 63, q = fe >> 6;
        int k = q >> 1, nt = q & 1;
        int w = nt*16 + (l & 15);
        int v = (l>>4)*8 + el;
        AFp[e] = (v < V_ && w < V_) ? f2bf(A[(k*V_ + v)*V_ + w]) : (ushort)0;
    }
    for (int e = tid; e < 4096; e += 256) {
        int c = e >> 5, w = e & 31;
        float s = 0.f;
        if (w < V_) {
            for (int k = 0; k < 3; ++k) {
                float cs = 0.f;
                for (int v = 0; v < V_; ++v) cs += A[(k*V_ + v)*V_ + w];
                s += bc[k*CO + c] * cs;
            }
        }
        BC2[e] = s;
    }
}

// ---------------- k1: MFMA forward; packed (y2,res) bf16 store via LDS staging; stats ----------------
// grid 2048; nb = blk>>5 (L2 affinity), tcb = blk&31; block 512 = 8 waves
__global__ __launch_bounds__(512, 2) void k1_main(
        const float* __restrict__ x, const float* __restrict__ bd,
        void* __restrict__ wsv, uint* __restrict__ outu) {
    char* wsb = (char*)wsv;
    const ushort* WCF = (const ushort*)(wsb + OFF_WCF);
    const ushort* WDF = (const ushort*)(wsb + OFF_WDF);
    const ushort* AF  = (const ushort*)(wsb + OFF_AF);
    const float*  BC2 = (const float*)(wsb + OFF_BC2);
    float* P1 = (float*)(wsb + OFF_P1);

    // 52224 B union: XR (16 KB) | BB0 (16 KB) | BB1 (16 KB); OST overlays all (51.2 KB)
    __shared__ uint SM[13056];
    ushort* XR  = (ushort*)SM;     // [ci64][t4][v32] bf16, 16B-slot XOR swizzle (2-bit key)
    short8* XR8 = (short8*)SM;
    uint*   XRu = SM;
    uint*   BBu0 = SM + 4096;      // B-frag buffers: [kb2][ntm8][lane64][8] ushort
    uint*   BBu1 = SM + 8192;
    short8* BB8_0 = (short8*)BBu0;
    short8* BB8_1 = (short8*)BBu1;
    uint*   OST = SM;              // staging for packed output (12800 uints)

    const int tid = threadIdx.x;
    const int l = tid & 63, wv = tid >> 6;
    const int blk = blockIdx.x;
    const int nb = blk >> 5, tcb = blk & 31;
    const long xbase = (long)nb * (CIN * T_ * V_);
    const int tg0 = tcb * 4;
    const int cbase = wv*16 + (l >> 4)*4;

    // ---- preload per-wave constants (global/L2, before any LDS dependency) ----
    short8 wcf[6];
    #pragma unroll
    for (int ks = 0; ks < 6; ++ks)
        wcf[ks] = *(const short8*)(WCF + ((wv*6 + ks)*64 + l)*8);
    const int t_a = wv & 3, nt_a = wv >> 2;
    short8 amv[3];
    #pragma unroll
    for (int k = 0; k < 3; ++k)
        amv[k] = *(const short8*)(AF + ((k*2 + nt_a)*64 + l)*8);
    short8 wdf[2];
    #pragma unroll
    for (int ks = 0; ks < 2; ++ks)
        wdf[ks] = *(const short8*)(WDF + ((wv*2 + ks)*64 + l)*8);
    float bdv[4];
    #pragma unroll
    for (int r = 0; r < 4; ++r) bdv[r] = bd[cbase + r];

    // ---- stage x -> XR ----
    #pragma unroll
    for (int i = 0; i < 8; ++i) {
        int p = tid + i * 512;
        int ci = p >> 6, rem = p & 63, t = rem >> 4, vp = rem & 15, v = vp * 2;
        float f0 = 0.f, f1 = 0.f;
        if (v < V_)     f0 = x[xbase + ci*(T_*V_) + (tg0 + t)*V_ + v];
        if (v + 1 < V_) f1 = x[xbase + ci*(T_*V_) + (tg0 + t)*V_ + v + 1];
        int idx = (ci*4 + t)*16 + 4*((v >> 3) ^ (ci & 3)) + ((v & 7) >> 1);
        XRu[idx] = pack2(f0, f1);
    }
    __syncthreads();   // B1

    // ---- main path: agg (MFMA) -> y2 GEMM (MFMA), BB double-buffered ----
    short8 xf[4];
    #pragma unroll
    for (int mt = 0; mt < 4; ++mt) {
        int ci = mt*16 + (l & 15), vg = l >> 4;
        xf[mt] = XR8[(ci*4 + t_a)*4 + (vg ^ (ci & 3))];
    }
    floatx4 acc[8];
    #pragma unroll
    for (int i = 0; i < 8; ++i) acc[i] = (floatx4){0,0,0,0};

    const int ntm_a = t_a*2 + nt_a;
    for (int k = 0; k < 3; ++k) {
        uint* bw = (k & 1) ? BBu1 : BBu0;
        const short8* br = (k & 1) ? BB8_1 : BB8_0;
        #pragma unroll
        for (int mt = 0; mt < 4; ++mt) {
            floatx4 agc = __builtin_amdgcn_mfma_f32_16x16x32_bf16(
                xf[mt], amv[k], (floatx4){0,0,0,0}, 0, 0, 0);
            int kb = mt >> 1;
            #pragma unroll
            for (int rp = 0; rp < 4; rp += 2) {
                int jo = (l >> 4)*4 + rp;
                int lf = (l & 15) + 16*((mt & 1)*2 + (jo >> 3));
                int ef = jo & 7;
                bw[(((kb*8 + ntm_a)*64 + lf)*16 + ef*2) >> 2] = pack2(agc[rp], agc[rp+1]);
            }
        }
        __syncthreads();   // B2/B3/B4 — one per k (dbuf makes read/write race-free)
        #pragma unroll
        for (int kb = 0; kb < 2; ++kb)
            #pragma unroll
            for (int m = 0; m < 8; ++m)
                acc[m] = __builtin_amdgcn_mfma_f32_16x16x32_bf16(
                    wcf[k*2 + kb], br[(kb*8 + m)*64 + l], acc[m], 0, 0, 0);
    }

    // ---- y2: add bias in-place, accumulate + reduce stats (no LDS) ----
    float ys[4] = {0,0,0,0}, yss[4] = {0,0,0,0};
    #pragma unroll
    for (int m = 0; m < 8; ++m) {
        int n = m*16 + (l & 15), w = n & 31;
        bool valid = w < V_;
        #pragma unroll
        for (int r = 0; r < 4; ++r) {
            float val = acc[m][r] + BC2[(cbase + r)*32 + w];
            acc[m][r] = val;
            if (valid) { ys[r] += val; yss[r] += val*val; }
        }
    }
    #pragma unroll
    for (int m = 1; m < 16; m <<= 1)
        #pragma unroll
        for (int r = 0; r < 4; ++r) {
            ys[r]  += __shfl_xor(ys[r],  m);
            yss[r] += __shfl_xor(yss[r], m);
        }
    if ((l & 15) == 0)
        #pragma unroll
        for (int r = 0; r < 4; ++r) {
            int c = cbase + r;
            P1[(0*128 + c)*2048 + blk] = ys[r];
            P1[(1*128 + c)*2048 + blk] = yss[r];
        }

    // ---- residual: rebuild BB1 with x B-frags (K=ci) — no pre-barrier needed ----
    #pragma unroll
    for (int i = 0; i < 2; ++i) {
        int task = tid + i*512;
        int fid = task >> 6, tl = task & 63;
        int n = (fid & 7)*16 + (tl & 15), t = n >> 5, v = n & 31;
        short8 r8;
        #pragma unroll
        for (int e = 0; e < 8; ++e) {
            int ci = (fid >> 3)*32 + (tl >> 4)*8 + e;
            r8[e] = (short)XR[(ci*4 + t)*32 + 8*((v >> 3) ^ (ci & 3)) + (v & 7)];
        }
        BB8_1[fid*64 + tl] = r8;
    }
    __syncthreads();   // B5

    floatx4 racc[8];
    #pragma unroll
    for (int i = 0; i < 8; ++i) racc[i] = (floatx4){0,0,0,0};
    #pragma unroll
    for (int ks = 0; ks < 2; ++ks)
        #pragma unroll
        for (int m = 0; m < 8; ++m)
            racc[m] = __builtin_amdgcn_mfma_f32_16x16x32_bf16(
                wdf[ks], BB8_1[(ks*8 + m)*64 + l], racc[m], 0, 0, 0);
    __syncthreads();   // B6 — all LDS reads done; OST may overlay

    // ---- pack (y2,res) into OST + residual stats ----
    float rs[4] = {0,0,0,0}, rss[4] = {0,0,0,0};
    #pragma unroll
    for (int m = 0; m < 8; ++m) {
        int n = m*16 + (l & 15), t = n >> 5, w = n & 31;
        if (w < V_) {
            #pragma unroll
            for (int r = 0; r < 4; ++r) {
                float rv = racc[m][r] + bdv[r];
                rs[r] += rv; rss[r] += rv*rv;
                OST[(cbase + r)*100 + t*25 + w] = pack2(acc[m][r], rv);
            }
        }
    }
    #pragma unroll
    for (int m = 1; m < 16; m <<= 1)
        #pragma unroll
        for (int r = 0; r < 4; ++r) {
            rs[r]  += __shfl_xor(rs[r],  m);
            rss[r] += __shfl_xor(rss[r], m);
        }
    if ((l & 15) == 0)
        #pragma unroll
        for (int r = 0; r < 4; ++r) {
            int c = cbase + r;
            P1[(2*128 + c)*2048 + blk] = rs[r];
            P1[(3*128 + c)*2048 + blk] = rss[r];
        }
    __syncthreads();   // B7

    // ---- coalesced bulk store: 400B contiguous run per channel ----
    const long ob = (long)nb * 409600 + (long)tg0 * 25;
    for (int task = tid; task < 3200; task += 512) {
        int c = (task * 1311) >> 15;        // task/25, exact on [0,3200)
        int q = task - c * 25;
        uint4 v4 = *(const uint4*)(OST + c*100 + q*4);
        *(uint4*)(outu + ob + (long)c*3200 + q*4) = v4;
    }
}

// ---------------- k2a/k2b: deterministic stat reduction + folding ----------------
__global__ void k2a(void* __restrict__ wsv) {
    char* wsb = (char*)wsv;
    const float* P1 = (const float*)(wsb + OFF_P1);
    float* SUM = (float*)(wsb + OFF_SUM);
    __shared__ float red[256];
    int gc = blockIdx.x;
    float s = 0.f;
    for (int i = threadIdx.x; i < 2048; i += 256) s += P1[(long)gc*2048 + i];
    red[threadIdx.x] = s; __syncthreads();
    for (int st = 128; st > 0; st >>= 1) {
        if (threadIdx.x < st) red[threadIdx.x] += red[threadIdx.x + st];
        __syncthreads();
    }
    if (threadIdx.x == 0) SUM[gc] = red[0];
}

__global__ void k2b(const float* __restrict__ gamma, const float* __restrict__ beta,
                    const float* __restrict__ gamma_d, const float* __restrict__ beta_d,
                    void* __restrict__ wsv) {
    char* wsb = (char*)wsv;
    const float* SUM = (const float*)(wsb + OFF_SUM);
    float* STAT = (float*)(wsb + OFF_STAT);
    int c = threadIdx.x;
    if (c < 128) {
        float my = SUM[c] / MCNT;
        float vy = fmaxf(SUM[128 + c] / MCNT - my*my, 0.f);
        float s1 = rsqrtf(vy + 1e-5f) * gamma[c];
        float h1 = beta[c] - my * s1;
        float mr = SUM[256 + c] / MCNT;     // res stats already include bd
        float vr = fmaxf(SUM[384 + c] / MCNT - mr*mr, 0.f);
        float s2 = rsqrtf(vr + 1e-5f) * gamma_d[c];
        float h2 = beta_d[c] - mr * s2;
        STAT[c] = s1; STAT[128 + c] = s2; STAT[256 + c] = h1 + h2;
    }
}

// ---------------- k3: in-place streaming map: packed(y2,res) -> relu(y2*s1+res*s2+h) ----------------
__global__ __launch_bounds__(256) void k3_map(void* __restrict__ wsv, uint* __restrict__ outu) {
    const float* STAT = (const float*)((const char*)wsv + OFF_STAT);
    __shared__ float sS[384];
    for (int i = threadIdx.x; i < 384; i += 256) sS[i] = STAT[i];
    __syncthreads();
    const int total4 = 6553600;                 // 26214400 uints / 4
    int stride = gridDim.x * blockDim.x;
    for (int j = blockIdx.x * blockDim.x + threadIdx.x; j < total4; j += stride) {
        uint4 u = ((const uint4*)outu)[j];
        int c = (j / 800) & 127;                // c = (4j / 3200) % 128
        float s1 = sS[c], s2 = sS[128 + c], h = sS[256 + c];
        float4 o;
        o.x = fmaxf(__uint_as_float(u.x << 16) * s1 + __uint_as_float(u.x & 0xFFFF0000u) * s2 + h, 0.f);
        o.y = fmaxf(__uint_as_float(u.y << 16) * s1 + __uint_as_float(u.y & 0xFFFF0000u) * s2 + h, 0.f);
        o.z = fmaxf(__uint_as_float(u.z << 16) * s1 + __uint_as_float(u.z & 0xFFFF0000u) * s2 + h, 0.f);
        o.w = fmaxf(__uint_as_float(u.w << 16) * s1 + __uint_as_float(u.w & 0xFFFF0000u) * s2 + h, 0.f);
        ((float4*)outu)[j] = o;
    }
}

extern "C" void kernel_launch(void* const* d_in, const int* in_sizes, int n_in,
                              void* d_out, int out_size, void* d_ws, size_t ws_size,
                              hipStream_t stream) {
    const float* x       = (const float*)d_in[0];
    const float* A       = (const float*)d_in[1];
    const float* Wc      = (const float*)d_in[2];
    const float* bc      = (const float*)d_in[3];
    const float* gamma   = (const float*)d_in[4];
    const float* beta    = (const float*)d_in[5];
    const float* Wd      = (const float*)d_in[6];
    const float* bd      = (const float*)d_in[7];
    const float* gamma_d = (const float*)d_in[8];
    const float* beta_d  = (const float*)d_in[9];
    uint* outu = (uint*)d_out;

    k0_prep<<<1, 256, 0, stream>>>(A, Wc, bc, Wd, d_ws);
    k1_main<<<2048, 512, 0, stream>>>(x, bd, d_ws, outu);
    k2a<<<512, 256, 0, stream>>>(d_ws);
    k2b<<<1, 128, 0, stream>>>(gamma, beta, gamma_d, beta_d, d_ws);
    k3_map<<<2048, 256, 0, stream>>>(d_ws, outu);
}